// Round 2
// baseline (391.075 us; speedup 1.0000x reference)
//
#include <hip/hip_runtime.h>
#include <math.h>

namespace {

constexpr int C_DIM = 4;
constexpr int D_DIM = 64;
constexpr int H_DIM = 160;
constexpr int W_DIM = 160;

constexpr int TH = 16;
constexpr int TW = 16;
constexpr int HALO = 5;
constexpr int EH = TH + 2 * HALO;  // 26
constexpr int EW = TW + 2 * HALO;  // 26
constexpr int XST = EW + 1;        // 27: odd stride -> <=2-way LDS conflicts
constexpr int MST = TW + 1;        // 17 float4s per row (odd)

constexpr int TILES_H = H_DIM / TH;  // 10
constexpr int TILES_W = W_DIM / TW;  // 10
constexpr int NBLOCKS = 2 * C_DIM * TILES_H * TILES_W;  // 800

constexpr float C1f = 1e-4f;
constexpr float C2f = 9e-4f;
constexpr float INV_N = 1.0f / (2.0f * 64.0f * 160.0f * 160.0f);

struct GW { float g[11]; };

}  // namespace

__global__ void zero_acc_kernel(float* acc) {
    if (threadIdx.x < C_DIM) acc[threadIdx.x] = 0.0f;
}

__global__ void finalize_kernel(const float* __restrict__ acc, float* __restrict__ out) {
    if (threadIdx.x < C_DIM) out[threadIdx.x] = 1.0f - acc[threadIdx.x] * INV_N;
}

__global__ __launch_bounds__(256, 3) void ssim3d_kernel(
    const float* __restrict__ img1, const float* __restrict__ img2,
    float* __restrict__ acc, GW gwp) {

    // ---- block decode: (b, c, h-tile, w-tile) ----
    const int bid = blockIdx.x;
    const int twi = bid % TILES_W;
    const int thi = (bid / TILES_W) % TILES_H;
    const int c   = (bid / (TILES_W * TILES_H)) % C_DIM;
    const int b   =  bid / (TILES_W * TILES_H * C_DIM);

    const int h0 = thi * TH;
    const int w0 = twi * TW;

    const size_t planeHW = (size_t)H_DIM * W_DIM;
    const size_t volbase = ((size_t)(b * C_DIM + c)) * D_DIM * planeHW;
    const float* __restrict__ p1 = img1 + volbase;
    const float* __restrict__ p2 = img2 + volbase;

    const bool interior = (h0 >= HALO) && (h0 + TH + HALO <= H_DIM) &&
                          (w0 >= HALO) && (w0 + TW + HALO <= W_DIM);

    // ---- LDS ----
    __shared__ float  xs[EH][XST];     // input slice x (stride 27)
    __shared__ float  ys[EH][XST];     // input slice y
    __shared__ float4 mid[EH][MST];    // W-conv of (x, y, x^2+y^2, x*y)
    __shared__ float  rbuf[4];

    const int tid = threadIdx.x;

    // P1: stage slice s into xs/ys (zero-padded at H/W edges)
    auto load_slice = [&](int s) {
        const float* __restrict__ b1 = p1 + (size_t)s * planeHW;
        const float* __restrict__ b2 = p2 + (size_t)s * planeHW;
        if (interior) {
#pragma unroll
            for (int it = 0; it < 3; ++it) {
                const int e = tid + it * 256;
                if (e < EH * EW) {
                    const int hh = e / EW;
                    const int ww = e - hh * EW;
                    const size_t gi = (size_t)(h0 - HALO + hh) * W_DIM +
                                      (w0 - HALO + ww);
                    xs[hh][ww] = b1[gi];
                    ys[hh][ww] = b2[gi];
                }
            }
        } else {
#pragma unroll
            for (int it = 0; it < 3; ++it) {
                const int e = tid + it * 256;
                if (e < EH * EW) {
                    const int hh = e / EW;
                    const int ww = e - hh * EW;
                    const int gh = h0 - HALO + hh;
                    const int gw = w0 - HALO + ww;
                    float xv = 0.0f, yv = 0.0f;
                    if (((unsigned)gh < (unsigned)H_DIM) &&
                        ((unsigned)gw < (unsigned)W_DIM)) {
                        const size_t gi = (size_t)gh * W_DIM + gw;
                        xv = b1[gi];
                        yv = b2[gi];
                    }
                    xs[hh][ww] = xv;
                    ys[hh][ww] = yv;
                }
            }
        }
    };

    // P2: W-conv. 104 workers (26 rows x 4 groups), each 4 consecutive w
    // outputs via a 14-wide register sliding window. Caller guards tid<104.
    auto wconv = [&]() {
        const int row = tid >> 2;
        const int wg  = (tid & 3) * 4;
        float xv[14], yv[14], qv[14], pv[14];
#pragma unroll
        for (int j = 0; j < 14; ++j) {
            const float x = xs[row][wg + j];
            const float y = ys[row][wg + j];
            xv[j] = x;
            yv[j] = y;
            qv[j] = fmaf(x, x, y * y);   // x^2 + y^2
            pv[j] = x * y;
        }
#pragma unroll
        for (int o = 0; o < 4; ++o) {
            float sx = 0.f, sy = 0.f, sq = 0.f, sp = 0.f;
#pragma unroll
            for (int t = 0; t < 11; ++t) {
                const float gt = gwp.g[t];
                sx = fmaf(gt, xv[o + t], sx);
                sy = fmaf(gt, yv[o + t], sy);
                sq = fmaf(gt, qv[o + t], sq);
                sp = fmaf(gt, pv[o + t], sp);
            }
            mid[row][wg + o] = make_float4(sx, sy, sq, sp);
        }
    };

    // P3: H-conv at this thread's (h,w); 11x ds_read_b128
    const int h_out = tid >> 4;
    const int w_out = tid & 15;
    auto hconv = [&]() -> float4 {
        float o0 = 0.f, o1 = 0.f, o2 = 0.f, o3 = 0.f;
#pragma unroll
        for (int t = 0; t < 11; ++t) {
            const float4 a = mid[h_out + t][w_out];
            const float gt = gwp.g[t];
            o0 = fmaf(gt, a.x, o0);
            o1 = fmaf(gt, a.y, o1);
            o2 = fmaf(gt, a.z, o2);
            o3 = fmaf(gt, a.w, o3);
        }
        return make_float4(o0, o1, o2, o3);
    };

    // ---- register sliding window along D (4 fields) ----
    float win[11][4];
#pragma unroll
    for (int i = 0; i < 11; ++i)
#pragma unroll
        for (int f = 0; f < 4; ++f) win[i][f] = 0.0f;

    float accum = 0.0f;

    load_slice(0);
    __syncthreads();

    // per iteration: [P2(s)] sync [P3(s) + shift + consume(s-5) + P1(s+1)] sync
    for (int s = 0; s < D_DIM + HALO; ++s) {
        if (s < D_DIM && tid < 104) wconv();
        __syncthreads();

        float4 o = make_float4(0.f, 0.f, 0.f, 0.f);
        if (s < D_DIM) o = hconv();

        // shift window, insert slice s (zeros past the end -> D zero-padding)
#pragma unroll
        for (int i = 0; i < 10; ++i) {
            win[i][0] = win[i + 1][0];
            win[i][1] = win[i + 1][1];
            win[i][2] = win[i + 1][2];
            win[i][3] = win[i + 1][3];
        }
        win[10][0] = o.x; win[10][1] = o.y; win[10][2] = o.z; win[10][3] = o.w;

        if (s >= HALO) {  // output d = s-5 complete
            float m1 = 0.f, m2 = 0.f, q = 0.f, pp = 0.f;
#pragma unroll
            for (int t = 0; t < 11; ++t) {
                const float gt = gwp.g[t];
                m1 = fmaf(gt, win[t][0], m1);
                m2 = fmaf(gt, win[t][1], m2);
                q  = fmaf(gt, win[t][2], q);
                pp = fmaf(gt, win[t][3], pp);
            }
            const float m1s = m1 * m1;
            const float m2s = m2 * m2;
            const float m12 = m1 * m2;
            const float spp = q - m1s - m2s;   // sigma1^2 + sigma2^2
            const float s12 = pp - m12;        // sigma12
            const float num = (2.0f * m12 + C1f) * (2.0f * s12 + C2f);
            const float den = (m1s + m2s + C1f) * (spp + C2f);
            accum += num / den;
        }

        if (s + 1 < D_DIM) load_slice(s + 1);
        __syncthreads();
    }

    // ---- block reduction, one atomic per block ----
#pragma unroll
    for (int off = 32; off > 0; off >>= 1) accum += __shfl_down(accum, off, 64);
    const int wave = tid >> 6;
    const int lane = tid & 63;
    if (lane == 0) rbuf[wave] = accum;
    __syncthreads();
    if (tid == 0) {
        atomicAdd(&acc[c], rbuf[0] + rbuf[1] + rbuf[2] + rbuf[3]);
    }
}

extern "C" void kernel_launch(void* const* d_in, const int* in_sizes, int n_in,
                              void* d_out, int out_size, void* d_ws, size_t ws_size,
                              hipStream_t stream) {
    const float* img1 = (const float*)d_in[0];
    const float* img2 = (const float*)d_in[1];
    float* out = (float*)d_out;
    float* acc = (float*)d_ws;  // 4 floats of scratch

    // Gaussian weights in float64 on host (matches numpy float64 -> float32)
    GW gw;
    {
        double gd[11];
        double ssum = 0.0;
        for (int i = 0; i < 11; ++i) {
            const double t = (double)(i - 5);
            gd[i] = exp(-(t * t) / 4.5);  // 2*sigma^2 = 4.5
            ssum += gd[i];
        }
        for (int i = 0; i < 11; ++i) gw.g[i] = (float)(gd[i] / ssum);
    }

    zero_acc_kernel<<<1, 64, 0, stream>>>(acc);
    ssim3d_kernel<<<NBLOCKS, 256, 0, stream>>>(img1, img2, acc, gw);
    finalize_kernel<<<1, 64, 0, stream>>>(acc, out);
}

// Round 3
// 278.190 us; speedup vs baseline: 1.4058x; 1.4058x over previous
//
#include <hip/hip_runtime.h>
#include <math.h>

namespace {

constexpr int C_DIM = 4;
constexpr int D_DIM = 64;
constexpr int H_DIM = 160;
constexpr int W_DIM = 160;

constexpr int TH = 16;
constexpr int TW = 16;
constexpr int HALO = 5;
constexpr int EH = 26;          // TH + 10
constexpr int EW = 26;          // TW + 10
constexpr int XST = 27;         // float stride of xs/ys rows
constexpr int MST = 17;         // float4 stride of mid rows
constexpr int NPIX = EH * EW;   // 676

constexpr int TILES_W = 10;
constexpr int TPC = 100;                    // tiles per (b,c)
constexpr int NBLOCKS = 2 * C_DIM * TPC;    // 800

constexpr float C1f = 1e-4f;
constexpr float C2f = 9e-4f;
constexpr float INV_N = 1.0f / (2.0f * 64.0f * 160.0f * 160.0f);

struct GW { float g[11]; };

}  // namespace

__global__ void finalize_kernel(const float* __restrict__ partial,
                                float* __restrict__ out) {
    const int tid = threadIdx.x;
    const int c = tid >> 6;       // wave -> channel
    const int lane = tid & 63;
    float s = 0.0f;
#pragma unroll
    for (int b = 0; b < 2; ++b)
        for (int i = lane; i < TPC; i += 64)
            s += partial[b * (C_DIM * TPC) + c * TPC + i];
#pragma unroll
    for (int off = 32; off > 0; off >>= 1) s += __shfl_down(s, off, 64);
    if (lane == 0 && c < C_DIM) out[c] = 1.0f - s * INV_N;
}

__global__ __launch_bounds__(256, 4) void ssim3d_kernel(
    const float* __restrict__ img1, const float* __restrict__ img2,
    float* __restrict__ partial, GW gwp) {

    // ---- block decode: (b, c, tile) ----
    const int bid = blockIdx.x;
    const int tile = bid % TPC;
    const int c = (bid / TPC) % C_DIM;
    const int b = bid / (TPC * C_DIM);
    const int thi = tile / TILES_W;
    const int twi = tile % TILES_W;
    const int h0 = thi * TH;
    const int w0 = twi * TW;

    const long planeHW = (long)H_DIM * W_DIM;
    const long volbase = (long)(b * C_DIM + c) * D_DIM * planeHW;
    // pointer at tile origin minus halo (may be logically OOB for edge tiles;
    // never dereferenced OOB thanks to predication)
    const long org = volbase + (long)(h0 - HALO) * W_DIM + (w0 - HALO);
    const float* __restrict__ p1 = img1 + org;
    const float* __restrict__ p2 = img2 + org;

    const bool interior = (h0 >= HALO) && (h0 + TH + HALO <= H_DIM) &&
                          (w0 >= HALO) && (w0 + TW + HALO <= W_DIM);

    // ---- LDS ----
    __shared__ float  xs[2][EH][XST];
    __shared__ float  ys[2][EH][XST];
    __shared__ float4 mid[EH][MST];
    __shared__ float  rbuf[4];

    const int tid = threadIdx.x;

    // decode the 3 staging positions of this thread once
    int hh_[3], ww_[3];
    bool live_[3], ok_[3];
#pragma unroll
    for (int k = 0; k < 3; ++k) {
        const int e = tid + k * 256;
        live_[k] = (e < NPIX);
        const int hh = e / EW;
        const int ww = e - hh * EW;
        hh_[k] = hh;
        ww_[k] = ww;
        const int gh = h0 - HALO + hh;
        const int gw = w0 - HALO + ww;
        ok_[k] = ((unsigned)gh < (unsigned)H_DIM) &&
                 ((unsigned)gw < (unsigned)W_DIM);
    }

    // issue global loads for slice s into registers
    auto fetch_slice = [&](int s, float lx[3], float ly[3]) {
        const long sb = (long)s * planeHW;
#pragma unroll
        for (int k = 0; k < 3; ++k) {
            lx[k] = 0.0f;
            ly[k] = 0.0f;
            const bool go = live_[k] && (interior || ok_[k]);
            if (go) {
                const long gi = sb + (long)hh_[k] * W_DIM + ww_[k];
                lx[k] = p1[gi];
                ly[k] = p2[gi];
            }
        }
    };

    // commit fetched registers to LDS buffer `buf`
    auto commit_slice = [&](int buf, const float lx[3], const float ly[3]) {
#pragma unroll
        for (int k = 0; k < 3; ++k) {
            if (live_[k]) {
                xs[buf][hh_[k]][ww_[k]] = lx[k];
                ys[buf][hh_[k]][ww_[k]] = ly[k];
            }
        }
    };

    // P2: W-conv of 4 fields. 416 outputs; row index varies fastest across
    // lanes (hh = idx%26) -> 26 distinct (27*hh mod 32) bank offsets, <=2-way.
    auto wconv = [&](int cur) {
        {
            const int idx = tid;
            const int hh = idx % EW;
            const int w  = idx / EW;
            float sx = 0.f, sy = 0.f, sq = 0.f, sp = 0.f;
#pragma unroll
            for (int t = 0; t < 11; ++t) {
                const float x = xs[cur][hh][w + t];
                const float y = ys[cur][hh][w + t];
                const float gt = gwp.g[t];
                sx = fmaf(gt, x, sx);
                sy = fmaf(gt, y, sy);
                sq = fmaf(gt, fmaf(x, x, y * y), sq);
                sp = fmaf(gt, x * y, sp);
            }
            mid[hh][w] = make_float4(sx, sy, sq, sp);
        }
        if (tid < EH * TW - 256) {  // 160 threads, outputs 256..415
            const int idx = tid + 256;
            const int hh = idx % EW;
            const int w  = idx / EW;
            float sx = 0.f, sy = 0.f, sq = 0.f, sp = 0.f;
#pragma unroll
            for (int t = 0; t < 11; ++t) {
                const float x = xs[cur][hh][w + t];
                const float y = ys[cur][hh][w + t];
                const float gt = gwp.g[t];
                sx = fmaf(gt, x, sx);
                sy = fmaf(gt, y, sy);
                sq = fmaf(gt, fmaf(x, x, y * y), sq);
                sp = fmaf(gt, x * y, sp);
            }
            mid[hh][w] = make_float4(sx, sy, sq, sp);
        }
    };

    // P3: H-conv at this thread's (h,w)
    const int h_out = tid >> 4;
    const int w_out = tid & 15;
    auto hconv = [&]() -> float4 {
        float o0 = 0.f, o1 = 0.f, o2 = 0.f, o3 = 0.f;
#pragma unroll
        for (int t = 0; t < 11; ++t) {
            const float4 a = mid[h_out + t][w_out];
            const float gt = gwp.g[t];
            o0 = fmaf(gt, a.x, o0);
            o1 = fmaf(gt, a.y, o1);
            o2 = fmaf(gt, a.z, o2);
            o3 = fmaf(gt, a.w, o3);
        }
        return make_float4(o0, o1, o2, o3);
    };

    // ---- D sliding window (4 fields), VGPR-resident ----
    float win[11][4];
#pragma unroll
    for (int i = 0; i < 11; ++i)
#pragma unroll
        for (int f = 0; f < 4; ++f) win[i][f] = 0.0f;

    float accum = 0.0f;

    auto consume = [&]() {
        float m1 = 0.f, m2 = 0.f, q = 0.f, pp = 0.f;
#pragma unroll
        for (int t = 0; t < 11; ++t) {
            const float gt = gwp.g[t];
            m1 = fmaf(gt, win[t][0], m1);
            m2 = fmaf(gt, win[t][1], m2);
            q  = fmaf(gt, win[t][2], q);
            pp = fmaf(gt, win[t][3], pp);
        }
        const float m1s = m1 * m1;
        const float m2s = m2 * m2;
        const float m12 = m1 * m2;
        const float spp = q - m1s - m2s;   // sigma1^2 + sigma2^2
        const float s12 = pp - m12;        // sigma12
        const float num = (2.0f * m12 + C1f) * (2.0f * s12 + C2f);
        const float den = (m1s + m2s + C1f) * (spp + C2f);
        accum = fmaf(num, __builtin_amdgcn_rcpf(den), accum);
    };

    auto shift_insert = [&](float4 o) {
#pragma unroll
        for (int i = 0; i < 10; ++i) {
            win[i][0] = win[i + 1][0];
            win[i][1] = win[i + 1][1];
            win[i][2] = win[i + 1][2];
            win[i][3] = win[i + 1][3];
        }
        win[10][0] = o.x; win[10][1] = o.y; win[10][2] = o.z; win[10][3] = o.w;
    };

    // preload slice 0 into buf 0
    {
        float lx[3], ly[3];
        fetch_slice(0, lx, ly);
        commit_slice(0, lx, ly);
    }
    __syncthreads();

    for (int s = 0; s < D_DIM; ++s) {
        const int cur = s & 1;
        // Phase A: issue next-slice loads, W-conv current, commit next slice
        float lx[3], ly[3];
        const bool have_next = (s + 1 < D_DIM);
        if (have_next) fetch_slice(s + 1, lx, ly);
        wconv(cur);
        if (have_next) commit_slice(cur ^ 1, lx, ly);
        __syncthreads();
        // Phase B: H-conv, D-window update, consume
        const float4 o = hconv();
        shift_insert(o);
        if (s >= HALO) consume();
        __syncthreads();
    }
    // D tail: slices 64..68 are zero padding
#pragma unroll
    for (int s = D_DIM; s < D_DIM + HALO; ++s) {
        shift_insert(make_float4(0.f, 0.f, 0.f, 0.f));
        consume();
    }

    // ---- block reduction -> one partial per block (no atomics) ----
#pragma unroll
    for (int off = 32; off > 0; off >>= 1) accum += __shfl_down(accum, off, 64);
    const int wave = tid >> 6;
    const int lane = tid & 63;
    if (lane == 0) rbuf[wave] = accum;
    __syncthreads();
    if (tid == 0) partial[bid] = rbuf[0] + rbuf[1] + rbuf[2] + rbuf[3];
}

extern "C" void kernel_launch(void* const* d_in, const int* in_sizes, int n_in,
                              void* d_out, int out_size, void* d_ws, size_t ws_size,
                              hipStream_t stream) {
    const float* img1 = (const float*)d_in[0];
    const float* img2 = (const float*)d_in[1];
    float* out = (float*)d_out;
    float* partial = (float*)d_ws;  // NBLOCKS floats of scratch

    // Gaussian weights in float64 on host (matches numpy float64 -> float32)
    GW gw;
    {
        double gd[11];
        double ssum = 0.0;
        for (int i = 0; i < 11; ++i) {
            const double t = (double)(i - 5);
            gd[i] = exp(-(t * t) / 4.5);  // 2*sigma^2 = 4.5
            ssum += gd[i];
        }
        for (int i = 0; i < 11; ++i) gw.g[i] = (float)(gd[i] / ssum);
    }

    ssim3d_kernel<<<NBLOCKS, 256, 0, stream>>>(img1, img2, partial, gw);
    finalize_kernel<<<1, 256, 0, stream>>>(partial, out);
}